// Round 1
// baseline (501.210 us; speedup 1.0000x reference)
//
#include <hip/hip_runtime.h>

#define Bb 4
#define Cc 256
#define Nn 4096

typedef __attribute__((ext_vector_type(8))) short bf16x8;
typedef __attribute__((ext_vector_type(4))) float f32x4;

__device__ __forceinline__ unsigned short f2bf(float f) {
    union { float f; unsigned u; } v; v.f = f;
    unsigned r = v.u + 0x7FFF + ((v.u >> 16) & 1);
    return (unsigned short)(r >> 16);
}

__device__ __forceinline__ void async_copy16(const void* g, void* l) {
    __builtin_amdgcn_global_load_lds(
        (const __attribute__((address_space(1))) unsigned int*)g,
        (__attribute__((address_space(3))) unsigned int*)l, 16, 0, 0);
}

// ---------------------------------------------------------------------------
// Kernel 1: value[b,o,n] = bf16( sum_c W[o,c]*X[b,c,n] + bias[o] )
// GEMM per batch: M=256(o), N=4096(n), K=256(c). Tile 128x128, BK=32.
// Grid: 4 * 2 * 32 = 256 blocks, 256 threads.
// ---------------------------------------------------------------------------
__global__ __launch_bounds__(256) void value_gemm(
    const float* __restrict__ X, const float* __restrict__ W,
    const float* __restrict__ bias, unsigned short* __restrict__ Vout)
{
    __shared__ unsigned short a_lds[128 * 32];  // W tile [o][c], bf16
    __shared__ unsigned short b_lds[128 * 32];  // X^T tile [n][c], bf16

    const int t = threadIdx.x;
    const int blk = blockIdx.x;
    const int b  = blk >> 6;
    const int r  = blk & 63;
    const int o0 = (r >> 5) * 128;
    const int n0 = (r & 31) * 128;

    const int wave = t >> 6, lane = t & 63;
    const int wm = wave >> 1, wn = wave & 1;
    const int lrow = lane & 15, lq = lane >> 4;

    f32x4 acc[4][4] = {};

    for (int c0 = 0; c0 < Cc; c0 += 32) {
        __syncthreads();
        // Stage A: W[o0+row][c0 + c4*4 ..], 128 rows x 32 cols
        #pragma unroll
        for (int k = 0; k < 4; ++k) {
            const int idx = t + 256 * k;
            const int row = idx >> 3, c4 = idx & 7;
            const float4 v = *(const float4*)&W[(size_t)(o0 + row) * Cc + c0 + c4 * 4];
            ushort4 h; h.x = f2bf(v.x); h.y = f2bf(v.y); h.z = f2bf(v.z); h.w = f2bf(v.w);
            *(ushort4*)&a_lds[row * 32 + c4 * 4] = h;
        }
        // Stage B (transposed): X[b][c0+rc][n0 + n4*4 ..] -> b_lds[n][c]
        #pragma unroll
        for (int k = 0; k < 4; ++k) {
            const int idx = t + 256 * k;
            const int rc = idx >> 5, n4 = idx & 31;
            const float4 v = *(const float4*)&X[((size_t)(b * Cc + c0 + rc)) * Nn + n0 + n4 * 4];
            b_lds[(n4 * 4 + 0) * 32 + rc] = f2bf(v.x);
            b_lds[(n4 * 4 + 1) * 32 + rc] = f2bf(v.y);
            b_lds[(n4 * 4 + 2) * 32 + rc] = f2bf(v.z);
            b_lds[(n4 * 4 + 3) * 32 + rc] = f2bf(v.w);
        }
        __syncthreads();

        bf16x8 af[4], bfr[4];
        #pragma unroll
        for (int i = 0; i < 4; ++i)
            af[i] = *(const bf16x8*)&a_lds[(wm * 64 + i * 16 + lrow) * 32 + lq * 8];
        #pragma unroll
        for (int i = 0; i < 4; ++i)
            bfr[i] = *(const bf16x8*)&b_lds[(wn * 64 + i * 16 + lrow) * 32 + lq * 8];
        #pragma unroll
        for (int mi = 0; mi < 4; ++mi)
            #pragma unroll
            for (int ni = 0; ni < 4; ++ni)
                acc[mi][ni] = __builtin_amdgcn_mfma_f32_16x16x32_bf16(
                    af[mi], bfr[ni], acc[mi][ni], 0, 0, 0);
    }

    // Epilogue: + bias, cast bf16. C/D layout: col=lane&15, row=lq*4+reg.
    #pragma unroll
    for (int mi = 0; mi < 4; ++mi) {
        #pragma unroll
        for (int ni = 0; ni < 4; ++ni) {
            #pragma unroll
            for (int rr = 0; rr < 4; ++rr) {
                const int o = o0 + wm * 64 + mi * 16 + lq * 4 + rr;
                const int n = n0 + wn * 64 + ni * 16 + lrow;
                Vout[((size_t)(b * Cc + o)) * Nn + n] = f2bf(acc[mi][ni][rr] + bias[o]);
            }
        }
    }
}

// ---------------------------------------------------------------------------
// Kernel 2: out[b,c,m] = gamma * (sum_n V[c,n]*exp(E[m,n])) / (sum_n exp(E[m,n]))
//                        + 2*X[b,c,m]
// GEMM per batch: M=256(c), N=4096(m), K=4096(n). Tile 128x128, BK=32.
// Softmax denominator accumulated inline over the K-loop (full n sweep).
// Grid: 4 * 2 * 32 = 256 blocks, 256 threads.
// ---------------------------------------------------------------------------
__global__ __launch_bounds__(256) void attn_gemm(
    const unsigned short* __restrict__ V, const float* __restrict__ E,
    const float* __restrict__ X, const float* __restrict__ gamma,
    float* __restrict__ Out)
{
    __shared__ unsigned short a_lds[128 * 32];  // V tile [c][n-chunk], bf16
    __shared__ unsigned short b_lds[128 * 32];  // exp(E) tile [m][n-chunk], bf16
    __shared__ float sum_lds[128];

    const int t = threadIdx.x;
    const int blk = blockIdx.x;
    const int b  = blk >> 6;
    const int r  = blk & 63;
    const int c0 = (r >> 5) * 128;
    const int m0 = (r & 31) * 128;

    const int wave = t >> 6, lane = t & 63;
    const int wm = wave >> 1, wn = wave & 1;
    const int lrow = lane & 15, lq = lane >> 4;

    f32x4 acc[4][4] = {};
    float sacc[4] = {0.f, 0.f, 0.f, 0.f};

    // A-staging address components (chunk idx = t and t+256; 4 chunks/row of 64B)
    const int arow0 = t >> 2;          // rows 0..63
    const int acol  = (t & 3) * 8;     // bf16 col offset (16B chunks)

    for (int k0 = 0; k0 < Nn; k0 += 32) {
        __syncthreads();
        // A: async global->LDS, V[b][c0+row][k0 + acol ..], 16B per lane
        async_copy16(&V[((size_t)(b * Cc + c0 + arow0)) * Nn + k0 + acol],
                     &a_lds[(size_t)t * 8]);
        async_copy16(&V[((size_t)(b * Cc + c0 + 64 + arow0)) * Nn + k0 + acol],
                     &a_lds[(size_t)(t + 256) * 8]);
        // B: E fp32 -> exp -> bf16, accumulate row sums
        #pragma unroll
        for (int k = 0; k < 4; ++k) {
            const int idx = t + 256 * k;
            const int rowm = idx >> 3, n4 = idx & 7;
            const float4 e = *(const float4*)&E[((size_t)b * Nn + m0 + rowm) * Nn + k0 + n4 * 4];
            const float e0 = __expf(e.x), e1 = __expf(e.y), e2 = __expf(e.z), e3 = __expf(e.w);
            sacc[k] += (e0 + e1) + (e2 + e3);
            ushort4 h; h.x = f2bf(e0); h.y = f2bf(e1); h.z = f2bf(e2); h.w = f2bf(e3);
            *(ushort4*)&b_lds[rowm * 32 + n4 * 4] = h;
        }
        __syncthreads();

        bf16x8 af[4], bfr[4];
        #pragma unroll
        for (int i = 0; i < 4; ++i)
            af[i] = *(const bf16x8*)&a_lds[(wm * 64 + i * 16 + lrow) * 32 + lq * 8];
        #pragma unroll
        for (int i = 0; i < 4; ++i)
            bfr[i] = *(const bf16x8*)&b_lds[(wn * 64 + i * 16 + lrow) * 32 + lq * 8];
        #pragma unroll
        for (int mi = 0; mi < 4; ++mi)
            #pragma unroll
            for (int ni = 0; ni < 4; ++ni)
                acc[mi][ni] = __builtin_amdgcn_mfma_f32_16x16x32_bf16(
                    af[mi], bfr[ni], acc[mi][ni], 0, 0, 0);
    }

    // Reduce row sums: 8 threads (t%8 = n4) share row t/8 + 32k — same wave.
    #pragma unroll
    for (int k = 0; k < 4; ++k) {
        float s = sacc[k];
        s += __shfl_xor(s, 1);
        s += __shfl_xor(s, 2);
        s += __shfl_xor(s, 4);
        if ((t & 7) == 0) sum_lds[(t >> 3) + 32 * k] = s;
    }
    __syncthreads();

    // Epilogue: divide by softmax denom, scale by gamma, add 2x.
    const float g = gamma[0];
    #pragma unroll
    for (int ni = 0; ni < 4; ++ni) {
        const int mloc = wn * 64 + ni * 16 + lrow;
        const float scale = g / sum_lds[mloc];
        const int m = m0 + mloc;
        #pragma unroll
        for (int mi = 0; mi < 4; ++mi) {
            #pragma unroll
            for (int rr = 0; rr < 4; ++rr) {
                const int c = c0 + wm * 64 + mi * 16 + lq * 4 + rr;
                const size_t off = ((size_t)(b * Cc + c)) * Nn + m;
                Out[off] = scale * acc[mi][ni][rr] + 2.0f * X[off];
            }
        }
    }
}

extern "C" void kernel_launch(void* const* d_in, const int* in_sizes, int n_in,
                              void* d_out, int out_size, void* d_ws, size_t ws_size,
                              hipStream_t stream) {
    const float* energy  = (const float*)d_in[0];  // [4,4096,4096]
    const float* x       = (const float*)d_in[1];  // [4,256,64,64]
    const float* value_w = (const float*)d_in[2];  // [256,256]
    const float* value_b = (const float*)d_in[3];  // [256]
    const float* gamma   = (const float*)d_in[4];  // [1]
    float* out = (float*)d_out;
    unsigned short* Vws = (unsigned short*)d_ws;   // 4*256*4096 bf16 = 8 MB

    value_gemm<<<256, 256, 0, stream>>>(x, value_w, value_b, Vws);
    attn_gemm<<<256, 256, 0, stream>>>(Vws, energy, x, gamma, out);
}

// Round 2
// 468.977 us; speedup vs baseline: 1.0687x; 1.0687x over previous
//
#include <hip/hip_runtime.h>

#define Bb 4
#define Cc 256
#define Nn 4096

typedef __attribute__((ext_vector_type(8))) short bf16x8;
typedef __attribute__((ext_vector_type(4))) float f32x4;

__device__ __forceinline__ unsigned short f2bf(float f) {
    union { float f; unsigned u; } v; v.f = f;
    unsigned r = v.u + 0x7FFF + ((v.u >> 16) & 1);
    return (unsigned short)(r >> 16);
}

// ---------------------------------------------------------------------------
// Kernel 1: value[b,o,n] = bf16( sum_c W[o,c]*X[b,c,n] + bias[o] )
// Tile 128(o) x 64(n), BK=64, 4 k-steps. Grid 4*2*64=512 blocks (2/CU),
// 256 threads (4 waves 2x2, wave tile 64o x 32n). Swizzled LDS (chunk^row&7).
// ---------------------------------------------------------------------------
__global__ __launch_bounds__(256) void value_gemm(
    const float* __restrict__ X, const float* __restrict__ W,
    const float* __restrict__ bias, unsigned short* __restrict__ Vout)
{
    __shared__ unsigned short a_lds[128 * 64];  // W tile [o][c]
    __shared__ unsigned short b_lds[64 * 64];   // X^T tile [n][c]

    const int t = threadIdx.x;
    const int b  = blockIdx.x >> 7;
    const int r  = blockIdx.x & 127;
    const int o0 = (r >> 6) << 7;   // 0 or 128
    const int n0 = (r & 63) << 6;   // 0..4032

    const int wave = t >> 6, lane = t & 63;
    const int wm = wave >> 1, wn = wave & 1;
    const int lrow = lane & 15, lq = lane >> 4;

    f32x4 acc[4][2] = {};

    for (int c0 = 0; c0 < Cc; c0 += 64) {
        __syncthreads();
        // A: W[o0+row][c0 + f*4], 128x64 fp32 -> bf16, swizzled chunks
        #pragma unroll
        for (int j = 0; j < 8; ++j) {
            const int q = t + 256 * j;
            const int row = q >> 4, f = q & 15;
            const float4 v = *(const float4*)&W[(size_t)(o0 + row) * Cc + c0 + f * 4];
            ushort4 h; h.x = f2bf(v.x); h.y = f2bf(v.y); h.z = f2bf(v.z); h.w = f2bf(v.w);
            const int addr = row * 64 + (((f >> 1) ^ (row & 7)) << 3) + ((f & 1) << 2);
            *(ushort4*)&a_lds[addr] = h;
        }
        // B: X[b][c0+cc][n0 + f*4] -> b_lds[n][c] transposed, swizzled
        #pragma unroll
        for (int j = 0; j < 4; ++j) {
            const int q = t + 256 * j;
            const int cc = q >> 4, f = q & 15;
            const float4 v = *(const float4*)&X[((size_t)(b * Cc + c0 + cc)) * Nn + n0 + f * 4];
            const float vv[4] = {v.x, v.y, v.z, v.w};
            #pragma unroll
            for (int e = 0; e < 4; ++e) {
                const int nn = f * 4 + e;
                b_lds[nn * 64 + (((cc >> 3) ^ (nn & 7)) << 3) + (cc & 7)] = f2bf(vv[e]);
            }
        }
        __syncthreads();

        bf16x8 af[2][4], bfr[2][2];
        #pragma unroll
        for (int kk = 0; kk < 2; ++kk) {
            #pragma unroll
            for (int oi = 0; oi < 4; ++oi) {
                const int row = wm * 64 + oi * 16 + lrow;
                af[kk][oi] = *(const bf16x8*)&a_lds[row * 64 + (((kk * 4 + lq) ^ (lrow & 7)) << 3)];
            }
            #pragma unroll
            for (int ni = 0; ni < 2; ++ni) {
                const int rn = wn * 32 + ni * 16 + lrow;
                bfr[kk][ni] = *(const bf16x8*)&b_lds[rn * 64 + (((kk * 4 + lq) ^ (lrow & 7)) << 3)];
            }
        }
        #pragma unroll
        for (int oi = 0; oi < 4; ++oi)
            #pragma unroll
            for (int ni = 0; ni < 2; ++ni)
                #pragma unroll
                for (int kk = 0; kk < 2; ++kk)
                    acc[oi][ni] = __builtin_amdgcn_mfma_f32_16x16x32_bf16(
                        af[kk][oi], bfr[kk][ni], acc[oi][ni], 0, 0, 0);
    }

    #pragma unroll
    for (int oi = 0; oi < 4; ++oi) {
        #pragma unroll
        for (int ni = 0; ni < 2; ++ni) {
            #pragma unroll
            for (int rr = 0; rr < 4; ++rr) {
                const int o = o0 + wm * 64 + oi * 16 + lq * 4 + rr;
                const int n = n0 + wn * 32 + ni * 16 + lrow;
                Vout[((size_t)(b * Cc + o)) * Nn + n] = f2bf(acc[oi][ni][rr] + bias[o]);
            }
        }
    }
}

// ---------------------------------------------------------------------------
// Kernel 2: out[b,c,m] = gamma*(sum_n V[c,n]*exp(E[m,n]))/(sum_n exp(E[m,n]))
//                        + 2*X[b,c,m]
// Block tile: full 256(c) x 64(m), BK=64, 64 k-steps. Grid 4*64=256 blocks,
// 512 threads (8 waves 4c x 2m, wave tile 64c x 32m).
// A (V bf16): direct global->VGPR, prefetched 2 steps ahead (L2-resident).
// B (exp(E)): E prefetched 1 step ahead in regs; exp -> bf16 -> double-
// buffered swizzled LDS. One barrier per k-step, no global_load_lds.
// ---------------------------------------------------------------------------
__global__ __launch_bounds__(512, 2) void attn_gemm(
    const unsigned short* __restrict__ V, const float* __restrict__ E,
    const float* __restrict__ X, const float* __restrict__ gamma,
    float* __restrict__ Out)
{
    __shared__ unsigned short b_lds[2][64 * 64];  // exp(E) tile [m][k], bf16
    __shared__ float sum_lds[64];

    const int t = threadIdx.x;
    const int b  = blockIdx.x >> 6;
    const int m0 = (blockIdx.x & 63) << 6;

    const int wave = t >> 6, lane = t & 63;
    const int wm = wave >> 1, wn = wave & 1;   // wm: 0..3 (c), wn: 0..1 (m)
    const int lrow = lane & 15, lq = lane >> 4;

    // E-staging coords: thread owns m-row (t>>3), two float4 at n4*4 and n4*4+32
    const int rowm = t >> 3;
    const int n4   = t & 7;
    const float* Ebase = E + (size_t)b * Nn * Nn + (size_t)(m0 + rowm) * Nn + n4 * 4;
    const unsigned short* Vb = V + (size_t)b * Cc * Nn;

    // swizzled LDS store offsets (fixed per thread): f=n4 and f=8+n4
    const int st0 = rowm * 64 + (((n4 >> 1) ^ (rowm & 7)) << 3) + ((n4 & 1) << 2);
    const int st1 = rowm * 64 + (((4 + (n4 >> 1)) ^ (rowm & 7)) << 3) + ((n4 & 1) << 2);

    // A-fragment row offsets
    size_t vrow[4];
    #pragma unroll
    for (int ci = 0; ci < 4; ++ci)
        vrow[ci] = (size_t)(wm * 64 + ci * 16 + lrow) * Nn + lq * 8;

    f32x4 acc[4][2] = {};
    float sacc = 0.f;

    bf16x8 vcur[2][4], vnext[2][4];
    float4 ena, enb;

    // ---- prologue: k=0 and k=1 in flight ----
    {
        float4 ea0 = *(const float4*)(Ebase + 0);
        float4 eb0 = *(const float4*)(Ebase + 32);
        #pragma unroll
        for (int kk = 0; kk < 2; ++kk)
            #pragma unroll
            for (int ci = 0; ci < 4; ++ci)
                vcur[kk][ci] = *(const bf16x8*)(Vb + vrow[ci] + kk * 32);
        ena = *(const float4*)(Ebase + 64);
        enb = *(const float4*)(Ebase + 96);
        #pragma unroll
        for (int kk = 0; kk < 2; ++kk)
            #pragma unroll
            for (int ci = 0; ci < 4; ++ci)
                vnext[kk][ci] = *(const bf16x8*)(Vb + vrow[ci] + 64 + kk * 32);
        // stage exp(E[k=0]) -> buf 0
        const float e0 = __expf(ea0.x), e1 = __expf(ea0.y), e2 = __expf(ea0.z), e3 = __expf(ea0.w);
        const float e4 = __expf(eb0.x), e5 = __expf(eb0.y), e6 = __expf(eb0.z), e7 = __expf(eb0.w);
        sacc += ((e0 + e1) + (e2 + e3)) + ((e4 + e5) + (e6 + e7));
        ushort4 h0; h0.x = f2bf(e0); h0.y = f2bf(e1); h0.z = f2bf(e2); h0.w = f2bf(e3);
        ushort4 h1; h1.x = f2bf(e4); h1.y = f2bf(e5); h1.z = f2bf(e6); h1.w = f2bf(e7);
        *(ushort4*)&b_lds[0][st0] = h0;
        *(ushort4*)&b_lds[0][st1] = h1;
        __syncthreads();
    }

    // ---- main loop ----
    #pragma unroll 2
    for (int k = 0; k < 64; ++k) {
        const int cur = k & 1;
        const int kx2 = ((k + 2) << 6) & (Nn - 1);   // wrap (values unused at tail)

        // issue loads for k+2 (consumed two iterations from now)
        float4 e2a = *(const float4*)(Ebase + kx2);
        float4 e2b = *(const float4*)(Ebase + kx2 + 32);
        bf16x8 v2[2][4];
        #pragma unroll
        for (int kk = 0; kk < 2; ++kk)
            #pragma unroll
            for (int ci = 0; ci < 4; ++ci)
                v2[kk][ci] = *(const bf16x8*)(Vb + vrow[ci] + kx2 + kk * 32);

        // stage exp(E[k+1]) -> buf cur^1
        if (k < 63) {
            const float e0 = __expf(ena.x), e1 = __expf(ena.y), e2 = __expf(ena.z), e3 = __expf(ena.w);
            const float e4 = __expf(enb.x), e5 = __expf(enb.y), e6 = __expf(enb.z), e7 = __expf(enb.w);
            sacc += ((e0 + e1) + (e2 + e3)) + ((e4 + e5) + (e6 + e7));
            ushort4 h0; h0.x = f2bf(e0); h0.y = f2bf(e1); h0.z = f2bf(e2); h0.w = f2bf(e3);
            ushort4 h1; h1.x = f2bf(e4); h1.y = f2bf(e5); h1.z = f2bf(e6); h1.w = f2bf(e7);
            *(ushort4*)&b_lds[cur ^ 1][st0] = h0;
            *(ushort4*)&b_lds[cur ^ 1][st1] = h1;
        }

        // compute on buf cur with V[k] (in regs)
        bf16x8 bfr[2][2];
        #pragma unroll
        for (int kk = 0; kk < 2; ++kk)
            #pragma unroll
            for (int mi = 0; mi < 2; ++mi) {
                const int rm = wn * 32 + mi * 16 + lrow;
                bfr[kk][mi] = *(const bf16x8*)&b_lds[cur][rm * 64 + (((kk * 4 + lq) ^ (lrow & 7)) << 3)];
            }
        #pragma unroll
        for (int ci = 0; ci < 4; ++ci)
            #pragma unroll
            for (int mi = 0; mi < 2; ++mi)
                #pragma unroll
                for (int kk = 0; kk < 2; ++kk)
                    acc[ci][mi] = __builtin_amdgcn_mfma_f32_16x16x32_bf16(
                        vcur[kk][ci], bfr[kk][mi], acc[ci][mi], 0, 0, 0);

        // rotate prefetch registers
        #pragma unroll
        for (int kk = 0; kk < 2; ++kk)
            #pragma unroll
            for (int ci = 0; ci < 4; ++ci) {
                vcur[kk][ci] = vnext[kk][ci];
                vnext[kk][ci] = v2[kk][ci];
            }
        ena = e2a; enb = e2b;
        __syncthreads();
    }

    // ---- softmax denominators: reduce 8 threads per m-row ----
    {
        float s = sacc;
        s += __shfl_xor(s, 1);
        s += __shfl_xor(s, 2);
        s += __shfl_xor(s, 4);
        if (n4 == 0) sum_lds[rowm] = s;
    }
    __syncthreads();

    // ---- epilogue ----
    const float g = gamma[0];
    #pragma unroll
    for (int mi = 0; mi < 2; ++mi) {
        const int mloc = wn * 32 + mi * 16 + lrow;
        const float scale = g / sum_lds[mloc];
        const int m = m0 + mloc;
        #pragma unroll
        for (int ci = 0; ci < 4; ++ci) {
            #pragma unroll
            for (int rr = 0; rr < 4; ++rr) {
                const int c = wm * 64 + ci * 16 + lq * 4 + rr;
                const size_t off = ((size_t)(b * Cc + c)) * Nn + m;
                Out[off] = scale * acc[ci][mi][rr] + 2.0f * X[off];
            }
        }
    }
}

extern "C" void kernel_launch(void* const* d_in, const int* in_sizes, int n_in,
                              void* d_out, int out_size, void* d_ws, size_t ws_size,
                              hipStream_t stream) {
    const float* energy  = (const float*)d_in[0];  // [4,4096,4096]
    const float* x       = (const float*)d_in[1];  // [4,256,64,64]
    const float* value_w = (const float*)d_in[2];  // [256,256]
    const float* value_b = (const float*)d_in[3];  // [256]
    const float* gamma   = (const float*)d_in[4];  // [1]
    float* out = (float*)d_out;
    unsigned short* Vws = (unsigned short*)d_ws;   // 4*256*4096 bf16 = 8 MB

    value_gemm<<<512, 256, 0, stream>>>(x, value_w, value_b, Vws);
    attn_gemm<<<256, 512, 0, stream>>>(Vws, energy, x, gamma, out);
}